// Round 13
// baseline (247.788 us; speedup 1.0000x reference)
//
#include <hip/hip_runtime.h>
#include <hip/hip_bf16.h>

typedef float        f32x4  __attribute__((ext_vector_type(4)));
typedef short        bf16x8 __attribute__((ext_vector_type(8)));
typedef unsigned int u32x4  __attribute__((ext_vector_type(4)));

#define HEADS 8
#define HID 64
#define IN_NODE 128
#define IN_EDGE 64
#define LDSP 69

// f32 -> bf16 (RNE), as raw bits in a short
static __device__ __forceinline__ short f2bf(float f) {
    unsigned u = __builtin_bit_cast(unsigned, f);
    unsigned r = (u + 0x7FFFu + ((u >> 16) & 1u)) >> 16;
    return (short)r;
}
static __device__ __forceinline__ float bflo(unsigned u) {
    return __builtin_bit_cast(float, u << 16);
}
static __device__ __forceinline__ float bfhi(unsigned u) {
    return __builtin_bit_cast(float, u & 0xFFFF0000u);
}

// ---------------------------------------------------------------------------
// QKV projection via MFMA. Q,K written as bf16 (K pre-scaled by 1/sqrt(8)),
// V stays f32. Verified R8-R12.
// ---------------------------------------------------------------------------
__global__ __launch_bounds__(256, 4) void qkv_kernel(
    const float* __restrict__ h,
    const float* __restrict__ WQ, const float* __restrict__ bQ,
    const float* __restrict__ WK, const float* __restrict__ bK,
    const float* __restrict__ WV, const float* __restrict__ bV,
    unsigned short* __restrict__ Qb, unsigned short* __restrict__ Kb,
    float* __restrict__ V, int n_nodes)
{
    const int lane = threadIdx.x & 63;
    const int r16  = lane & 15;
    const int g4   = lane >> 4;
    const int wave   = blockIdx.x * (blockDim.x >> 6) + (threadIdx.x >> 6);
    const int nwaves = gridDim.x * (blockDim.x >> 6);
    const int mat  = blockIdx.y;

    const float* __restrict__ W  = (mat == 0) ? WQ : (mat == 1) ? WK : WV;
    const float* __restrict__ bp = (mat == 0) ? bQ : (mat == 1) ? bK : bV;

    bf16x8 bfr[4][4];
#pragma unroll
    for (int ct = 0; ct < 4; ++ct)
#pragma unroll
        for (int kc = 0; kc < 4; ++kc)
#pragma unroll
            for (int j = 0; j < 8; ++j) {
                int k = kc * 32 + g4 * 8 + j;
                bfr[ct][kc][j] = f2bf(W[k * HID + ct * 16 + r16]);
            }
    float bias[4];
#pragma unroll
    for (int ct = 0; ct < 4; ++ct) bias[ct] = bp[ct * 16 + r16];

    const float SC = 0.35355339059327373f;
    const int ntiles = (n_nodes + 15) >> 4;
    for (int tile = wave; tile < ntiles; tile += nwaves) {
        const int row0 = tile * 16;
        int arow = row0 + r16; if (arow > n_nodes - 1) arow = n_nodes - 1;
        const float* ap = h + (size_t)arow * IN_NODE + g4 * 8;

        bf16x8 afr[4];
#pragma unroll
        for (int kc = 0; kc < 4; ++kc) {
            f32x4 p0 = *reinterpret_cast<const f32x4*>(ap + kc * 32);
            f32x4 p1 = *reinterpret_cast<const f32x4*>(ap + kc * 32 + 4);
            afr[kc][0] = f2bf(p0.x); afr[kc][1] = f2bf(p0.y);
            afr[kc][2] = f2bf(p0.z); afr[kc][3] = f2bf(p0.w);
            afr[kc][4] = f2bf(p1.x); afr[kc][5] = f2bf(p1.y);
            afr[kc][6] = f2bf(p1.z); afr[kc][7] = f2bf(p1.w);
        }

        f32x4 acc[4] = {};
#pragma unroll
        for (int ct = 0; ct < 4; ++ct)
#pragma unroll
            for (int kc = 0; kc < 4; ++kc)
                acc[ct] = __builtin_amdgcn_mfma_f32_16x16x32_bf16(
                    afr[kc], bfr[ct][kc], acc[ct], 0, 0, 0);

#pragma unroll
        for (int ct = 0; ct < 4; ++ct)
#pragma unroll
            for (int r = 0; r < 4; ++r) {
                int orow = row0 + g4 * 4 + r;
                if (orow < n_nodes) {
                    float val = acc[ct][r] + bias[ct];
                    size_t idx = (size_t)orow * HID + ct * 16 + r16;
                    if (mat == 0)      Qb[idx] = (unsigned short)f2bf(val);
                    else if (mat == 1) Kb[idx] = (unsigned short)f2bf(val * SC);
                    else               V[idx]  = val;
                }
            }
    }
}

// ---------------------------------------------------------------------------
// Edge kernel = R12 structure with SINGLE-buffer LDS (17664B/block, was
// 35328): same-wave DS ordering makes buffer reuse safe (epilogue-u0 reads
// issue before u1 remap writes; DS ops of one wave execute in order).
// Doubles the LDS-side block/CU cap; VGPR (~80, bounds 256,4 - no spill)
// now binds at 16 waves/CU.
// ---------------------------------------------------------------------------
__global__ __launch_bounds__(256, 4) void edge_kernel(
    const int* __restrict__ ei, const float* __restrict__ e,
    const float* __restrict__ We, const float* __restrict__ be,
    const unsigned short* __restrict__ Qb, const unsigned short* __restrict__ Kb,
    float* __restrict__ e_out, float* __restrict__ z_sum,
    float* __restrict__ cnt, int n_edges, int tpw)
{
    const int lane = threadIdx.x & 63;
    const int wid  = threadIdx.x >> 6;
    const int r16  = lane & 15;
    const int g4   = lane >> 4;
    const int el   = lane >> 2;   // epilogue: edge-local 0..15
    const int qg   = lane & 3;    // epilogue: col-quad 0..3

    __shared__ float plds[4][16][LDSP];
    float (*my)[LDSP] = plds[wid];

    const int wave = blockIdx.x * 4 + wid;
    const int ntiles = (n_edges + 15) >> 4;
    int t0 = wave * tpw;
    int t1 = t0 + tpw; if (t1 > ntiles) t1 = ntiles;
    if (t0 >= t1) return;

    bf16x8 bfr[4][2];
#pragma unroll
    for (int ct = 0; ct < 4; ++ct)
#pragma unroll
        for (int kc = 0; kc < 2; ++kc)
#pragma unroll
            for (int j = 0; j < 8; ++j) {
                int k = kc * 32 + g4 * 8 + j;
                bfr[ct][kc][j] = f2bf(We[k * HID + ct * 16 + r16]);
            }
    float bias[4];
#pragma unroll
    for (int ct = 0; ct < 4; ++ct) bias[ct] = be[ct * 16 + r16];

    const unsigned* Kbu = reinterpret_cast<const unsigned*>(Kb);
    const unsigned* Qbu = reinterpret_cast<const unsigned*>(Qb);

    // pipeline state: current pair (C) and next pair (N)
    f32x4 evC[2][4], evN[2][4];
    int srcC[2], dstC[2], srcN[2], dstN[2];

    // prologue: load pair t0 (e rows + indices)
#pragma unroll
    for (int u = 0; u < 2; ++u) {
        int tt = t0 + u; if (tt > ntiles - 1) tt = ntiles - 1;
        int arow = tt * 16 + r16; if (arow > n_edges - 1) arow = n_edges - 1;
        const float* ap = e + (size_t)arow * IN_EDGE + g4 * 8;
        evC[u][0] = __builtin_nontemporal_load(reinterpret_cast<const f32x4*>(ap));
        evC[u][1] = __builtin_nontemporal_load(reinterpret_cast<const f32x4*>(ap + 4));
        evC[u][2] = __builtin_nontemporal_load(reinterpret_cast<const f32x4*>(ap + 32));
        evC[u][3] = __builtin_nontemporal_load(reinterpret_cast<const f32x4*>(ap + 36));
        int erc = tt * 16 + el; if (erc > n_edges - 1) erc = n_edges - 1;
        srcC[u] = ei[erc];
        dstC[u] = ei[n_edges + erc];
    }

    for (int t = t0; t < t1; t += 2) {
        // ---- K/Q gathers for current pair (indices arrived an iter ago) ----
        u32x4 kb[2][2], qb[2][2];
#pragma unroll
        for (int u = 0; u < 2; ++u) {
            const unsigned* kp = Kbu + (size_t)srcC[u] * 32 + qg * 8;
            const unsigned* qp = Qbu + (size_t)dstC[u] * 32 + qg * 8;
            kb[u][0] = *reinterpret_cast<const u32x4*>(kp);
            kb[u][1] = *reinterpret_cast<const u32x4*>(kp + 4);
            qb[u][0] = *reinterpret_cast<const u32x4*>(qp);
            qb[u][1] = *reinterpret_cast<const u32x4*>(qp + 4);
        }

        // ---- prefetch pair t+2 (e rows + indices) ----
        {
            int tn = t + 2; if (tn > t1 - 1) tn = t1 - 1;
#pragma unroll
            for (int u = 0; u < 2; ++u) {
                int tt = tn + u; if (tt > ntiles - 1) tt = ntiles - 1;
                int arow = tt * 16 + r16; if (arow > n_edges - 1) arow = n_edges - 1;
                const float* ap = e + (size_t)arow * IN_EDGE + g4 * 8;
                evN[u][0] = __builtin_nontemporal_load(reinterpret_cast<const f32x4*>(ap));
                evN[u][1] = __builtin_nontemporal_load(reinterpret_cast<const f32x4*>(ap + 4));
                evN[u][2] = __builtin_nontemporal_load(reinterpret_cast<const f32x4*>(ap + 32));
                evN[u][3] = __builtin_nontemporal_load(reinterpret_cast<const f32x4*>(ap + 36));
                int erc = tt * 16 + el; if (erc > n_edges - 1) erc = n_edges - 1;
                srcN[u] = ei[erc];
                dstN[u] = ei[n_edges + erc];
            }
        }

        // ---- per tile: MFMA + remap -> lgkm wait -> epilogue (buffer reuse) --
#pragma unroll
        for (int u = 0; u < 2; ++u) {
            bf16x8 afr[2];
            afr[0][0] = f2bf(evC[u][0].x); afr[0][1] = f2bf(evC[u][0].y);
            afr[0][2] = f2bf(evC[u][0].z); afr[0][3] = f2bf(evC[u][0].w);
            afr[0][4] = f2bf(evC[u][1].x); afr[0][5] = f2bf(evC[u][1].y);
            afr[0][6] = f2bf(evC[u][1].z); afr[0][7] = f2bf(evC[u][1].w);
            afr[1][0] = f2bf(evC[u][2].x); afr[1][1] = f2bf(evC[u][2].y);
            afr[1][2] = f2bf(evC[u][2].z); afr[1][3] = f2bf(evC[u][2].w);
            afr[1][4] = f2bf(evC[u][3].x); afr[1][5] = f2bf(evC[u][3].y);
            afr[1][6] = f2bf(evC[u][3].z); afr[1][7] = f2bf(evC[u][3].w);

            f32x4 acc[4] = {};
#pragma unroll
            for (int ct = 0; ct < 4; ++ct) {
                acc[ct] = __builtin_amdgcn_mfma_f32_16x16x32_bf16(afr[0], bfr[ct][0], acc[ct], 0, 0, 0);
                acc[ct] = __builtin_amdgcn_mfma_f32_16x16x32_bf16(afr[1], bfr[ct][1], acc[ct], 0, 0, 0);
            }
#pragma unroll
            for (int ct = 0; ct < 4; ++ct)
#pragma unroll
                for (int r = 0; r < 4; ++r)
                    my[g4 * 4 + r][ct * 16 + r16] = acc[ct][r] + bias[ct];

            asm volatile("s_waitcnt lgkmcnt(0)" ::: "memory");

            const int tt = t + u;
            const int erow = tt * 16 + el;
            const bool valid = (tt < t1) && (erow < n_edges);

            const float* mrow = &my[el][qg * 16];
            f32x4 p0 = *reinterpret_cast<const f32x4*>(mrow);
            f32x4 p1 = *reinterpret_cast<const f32x4*>(mrow + 4);
            f32x4 p2 = *reinterpret_cast<const f32x4*>(mrow + 8);
            f32x4 p3 = *reinterpret_cast<const f32x4*>(mrow + 12);
            float pe[16];
            pe[0]=p0.x; pe[1]=p0.y; pe[2]=p0.z; pe[3]=p0.w;
            pe[4]=p1.x; pe[5]=p1.y; pe[6]=p1.z; pe[7]=p1.w;
            pe[8]=p2.x; pe[9]=p2.y; pe[10]=p2.z; pe[11]=p2.w;
            pe[12]=p3.x; pe[13]=p3.y; pe[14]=p3.z; pe[15]=p3.w;

            float sc[16];
#pragma unroll
            for (int half = 0; half < 2; ++half)
#pragma unroll
                for (int w = 0; w < 4; ++w) {
                    unsigned ku = kb[u][half][w];
                    unsigned qu = qb[u][half][w];
                    int c = half * 8 + 2 * w;
                    sc[c]     = fmaf(bflo(ku), bflo(qu), pe[c]);
                    sc[c + 1] = fmaf(bfhi(ku), bfhi(qu), pe[c + 1]);
                }

            if (valid) {
                float* op = e_out + (size_t)erow * HID + qg * 16;
                f32x4 s0 = {sc[0], sc[1], sc[2], sc[3]};
                f32x4 s1 = {sc[4], sc[5], sc[6], sc[7]};
                f32x4 s2 = {sc[8], sc[9], sc[10], sc[11]};
                f32x4 s3 = {sc[12], sc[13], sc[14], sc[15]};
                *reinterpret_cast<f32x4*>(op)      = s0;
                *reinterpret_cast<f32x4*>(op + 4)  = s1;
                *reinterpret_cast<f32x4*>(op + 8)  = s2;
                *reinterpret_cast<f32x4*>(op + 12) = s3;
            }

            float hs0 = ((sc[0] + sc[1]) + (sc[2] + sc[3])) + ((sc[4] + sc[5]) + (sc[6] + sc[7]));
            float hs1 = ((sc[8] + sc[9]) + (sc[10] + sc[11])) + ((sc[12] + sc[13]) + (sc[14] + sc[15]));
            float a0 = __expf(fminf(fmaxf(hs0, -5.0f), 5.0f));
            float a1 = __expf(fminf(fmaxf(hs1, -5.0f), 5.0f));
            if (valid) {
                atomicAdd(&z_sum[srcC[u] * HEADS + qg * 2], a0);
                atomicAdd(&z_sum[srcC[u] * HEADS + qg * 2 + 1], a1);
                if (qg == 0) atomicAdd(&cnt[srcC[u]], 1.0f);
            }
        }

        // ---- rotate pipeline ----
#pragma unroll
        for (int u = 0; u < 2; ++u) {
#pragma unroll
            for (int i = 0; i < 4; ++i) evC[u][i] = evN[u][i];
            srcC[u] = srcN[u]; dstC[u] = dstN[u];
        }
    }
}

// ---------------------------------------------------------------------------
// Finalize: h_out[n,h,d] = V[n,h,d]*S / (S/max(cnt,1) + 1e-6)
// ---------------------------------------------------------------------------
__global__ __launch_bounds__(256) void finalize_kernel(
    const float* __restrict__ V, const float* __restrict__ z_sum,
    const float* __restrict__ cnt, float* __restrict__ h_out, int total)
{
    int i = blockIdx.x * 256 + threadIdx.x;
    if (i >= total) return;
    int node = i >> 6;
    int head = (i >> 3) & 7;
    float S = z_sum[node * HEADS + head];
    float c = fmaxf(cnt[node], 1.0f);
    h_out[i] = V[i] * S / (S / c + 1e-6f);
}

extern "C" void kernel_launch(void* const* d_in, const int* in_sizes, int n_in,
                              void* d_out, int out_size, void* d_ws, size_t ws_size,
                              hipStream_t stream)
{
    const int*   ei = (const int*)d_in[0];
    const float* h  = (const float*)d_in[1];
    const float* e  = (const float*)d_in[2];
    const float* WQ = (const float*)d_in[3];
    const float* bQ = (const float*)d_in[4];
    const float* WK = (const float*)d_in[5];
    const float* bK = (const float*)d_in[6];
    const float* WV = (const float*)d_in[7];
    const float* bV = (const float*)d_in[8];
    const float* We = (const float*)d_in[9];
    const float* be = (const float*)d_in[10];

    const int n_nodes = in_sizes[1] / IN_NODE;   // 50000
    const int n_edges = in_sizes[2] / IN_EDGE;   // 800000

    float* out_h = (float*)d_out;                       // n_nodes*64
    float* out_e = out_h + (size_t)n_nodes * HID;       // n_edges*64

    unsigned short* Qb = (unsigned short*)d_ws;          // bf16, n*64
    unsigned short* Kb = Qb + (size_t)n_nodes * HID;     // bf16 (pre-scaled)
    float* V     = (float*)(Kb + (size_t)n_nodes * HID);
    float* z_sum = V + (size_t)n_nodes * HID;
    float* cnt   = z_sum + (size_t)n_nodes * HEADS;

    (void)hipMemsetAsync(z_sum, 0, (size_t)n_nodes * (HEADS + 1) * sizeof(float), stream);

    // QKV: 256 blocks x 4 waves x 3 mats
    {
        dim3 grid(256, 3);
        qkv_kernel<<<grid, 256, 0, stream>>>(h, WQ, bQ, WK, bK, WV, bV,
                                             Qb, Kb, V, n_nodes);
    }
    // Edge: 2048 blocks x 4 waves
    {
        const int nblk = 2048;
        const int nwaves = nblk * 4;
        const int ntiles = (n_edges + 15) >> 4;
        const int tpw = (ntiles + nwaves - 1) / nwaves;
        edge_kernel<<<nblk, 256, 0, stream>>>(ei, e, We, be, Qb, Kb,
                                              out_e, z_sum, cnt, n_edges, tpw);
    }
    // Finalize
    {
        const int total = n_nodes * HID;
        finalize_kernel<<<(total + 255) / 256, 256, 0, stream>>>(V, z_sum, cnt,
                                                                 out_h, total);
    }
}

// Round 14
// 219.126 us; speedup vs baseline: 1.1308x; 1.1308x over previous
//
#include <hip/hip_runtime.h>
#include <hip/hip_bf16.h>

typedef float        f32x4  __attribute__((ext_vector_type(4)));
typedef short        bf16x8 __attribute__((ext_vector_type(8)));
typedef unsigned int u32x4  __attribute__((ext_vector_type(4)));

#define HEADS 8
#define HID 64
#define IN_NODE 128
#define IN_EDGE 64
#define LDSP 69

// f32 -> bf16 (RNE), as raw bits in a short
static __device__ __forceinline__ short f2bf(float f) {
    unsigned u = __builtin_bit_cast(unsigned, f);
    unsigned r = (u + 0x7FFFu + ((u >> 16) & 1u)) >> 16;
    return (short)r;
}
static __device__ __forceinline__ float bflo(unsigned u) {
    return __builtin_bit_cast(float, u << 16);
}
static __device__ __forceinline__ float bfhi(unsigned u) {
    return __builtin_bit_cast(float, u & 0xFFFF0000u);
}

// ---------------------------------------------------------------------------
// QKV projection via MFMA. Q,K written as bf16 (K pre-scaled by 1/sqrt(8)),
// V stays f32. Verified R8-R13.
// ---------------------------------------------------------------------------
__global__ __launch_bounds__(256, 4) void qkv_kernel(
    const float* __restrict__ h,
    const float* __restrict__ WQ, const float* __restrict__ bQ,
    const float* __restrict__ WK, const float* __restrict__ bK,
    const float* __restrict__ WV, const float* __restrict__ bV,
    unsigned short* __restrict__ Qb, unsigned short* __restrict__ Kb,
    float* __restrict__ V, int n_nodes)
{
    const int lane = threadIdx.x & 63;
    const int r16  = lane & 15;
    const int g4   = lane >> 4;
    const int wave   = blockIdx.x * (blockDim.x >> 6) + (threadIdx.x >> 6);
    const int nwaves = gridDim.x * (blockDim.x >> 6);
    const int mat  = blockIdx.y;

    const float* __restrict__ W  = (mat == 0) ? WQ : (mat == 1) ? WK : WV;
    const float* __restrict__ bp = (mat == 0) ? bQ : (mat == 1) ? bK : bV;

    bf16x8 bfr[4][4];
#pragma unroll
    for (int ct = 0; ct < 4; ++ct)
#pragma unroll
        for (int kc = 0; kc < 4; ++kc)
#pragma unroll
            for (int j = 0; j < 8; ++j) {
                int k = kc * 32 + g4 * 8 + j;
                bfr[ct][kc][j] = f2bf(W[k * HID + ct * 16 + r16]);
            }
    float bias[4];
#pragma unroll
    for (int ct = 0; ct < 4; ++ct) bias[ct] = bp[ct * 16 + r16];

    const float SC = 0.35355339059327373f;
    const int ntiles = (n_nodes + 15) >> 4;
    for (int tile = wave; tile < ntiles; tile += nwaves) {
        const int row0 = tile * 16;
        int arow = row0 + r16; if (arow > n_nodes - 1) arow = n_nodes - 1;
        const float* ap = h + (size_t)arow * IN_NODE + g4 * 8;

        bf16x8 afr[4];
#pragma unroll
        for (int kc = 0; kc < 4; ++kc) {
            f32x4 p0 = *reinterpret_cast<const f32x4*>(ap + kc * 32);
            f32x4 p1 = *reinterpret_cast<const f32x4*>(ap + kc * 32 + 4);
            afr[kc][0] = f2bf(p0.x); afr[kc][1] = f2bf(p0.y);
            afr[kc][2] = f2bf(p0.z); afr[kc][3] = f2bf(p0.w);
            afr[kc][4] = f2bf(p1.x); afr[kc][5] = f2bf(p1.y);
            afr[kc][6] = f2bf(p1.z); afr[kc][7] = f2bf(p1.w);
        }

        f32x4 acc[4] = {};
#pragma unroll
        for (int ct = 0; ct < 4; ++ct)
#pragma unroll
            for (int kc = 0; kc < 4; ++kc)
                acc[ct] = __builtin_amdgcn_mfma_f32_16x16x32_bf16(
                    afr[kc], bfr[ct][kc], acc[ct], 0, 0, 0);

#pragma unroll
        for (int ct = 0; ct < 4; ++ct)
#pragma unroll
            for (int r = 0; r < 4; ++r) {
                int orow = row0 + g4 * 4 + r;
                if (orow < n_nodes) {
                    float val = acc[ct][r] + bias[ct];
                    size_t idx = (size_t)orow * HID + ct * 16 + r16;
                    if (mat == 0)      Qb[idx] = (unsigned short)f2bf(val);
                    else if (mat == 1) Kb[idx] = (unsigned short)f2bf(val * SC);
                    else               V[idx]  = val;
                }
            }
    }
}

// ---------------------------------------------------------------------------
// Edge kernel — R12 exact restore (best measured: edge 182us, total 220us).
// 2-tile pair per iteration, double-buffered LDS remap, cross-pair prefetch,
// 4 blocks/CU (the measured concurrency sweet spot: higher thrashes L2,
// inflating FETCH/WRITE 15-40% — R13).
// ---------------------------------------------------------------------------
__global__ __launch_bounds__(256, 3) void edge_kernel(
    const int* __restrict__ ei, const float* __restrict__ e,
    const float* __restrict__ We, const float* __restrict__ be,
    const unsigned short* __restrict__ Qb, const unsigned short* __restrict__ Kb,
    float* __restrict__ e_out, float* __restrict__ z_sum,
    float* __restrict__ cnt, int n_edges, int tpw)
{
    const int lane = threadIdx.x & 63;
    const int wid  = threadIdx.x >> 6;
    const int r16  = lane & 15;
    const int g4   = lane >> 4;
    const int el   = lane >> 2;   // epilogue: edge-local 0..15
    const int qg   = lane & 3;    // epilogue: col-quad 0..3

    __shared__ float plds[4][2][16][LDSP];

    const int wave = blockIdx.x * 4 + wid;
    const int ntiles = (n_edges + 15) >> 4;
    int t0 = wave * tpw;
    int t1 = t0 + tpw; if (t1 > ntiles) t1 = ntiles;
    if (t0 >= t1) return;

    bf16x8 bfr[4][2];
#pragma unroll
    for (int ct = 0; ct < 4; ++ct)
#pragma unroll
        for (int kc = 0; kc < 2; ++kc)
#pragma unroll
            for (int j = 0; j < 8; ++j) {
                int k = kc * 32 + g4 * 8 + j;
                bfr[ct][kc][j] = f2bf(We[k * HID + ct * 16 + r16]);
            }
    float bias[4];
#pragma unroll
    for (int ct = 0; ct < 4; ++ct) bias[ct] = be[ct * 16 + r16];

    const unsigned* Kbu = reinterpret_cast<const unsigned*>(Kb);
    const unsigned* Qbu = reinterpret_cast<const unsigned*>(Qb);

    // pipeline state: current pair (C) and next pair (N)
    f32x4 evC[2][4], evN[2][4];
    int srcC[2], dstC[2], srcN[2], dstN[2];

    // prologue: load pair t0 (e rows + indices)
#pragma unroll
    for (int u = 0; u < 2; ++u) {
        int tt = t0 + u; if (tt > ntiles - 1) tt = ntiles - 1;
        int arow = tt * 16 + r16; if (arow > n_edges - 1) arow = n_edges - 1;
        const float* ap = e + (size_t)arow * IN_EDGE + g4 * 8;
        evC[u][0] = __builtin_nontemporal_load(reinterpret_cast<const f32x4*>(ap));
        evC[u][1] = __builtin_nontemporal_load(reinterpret_cast<const f32x4*>(ap + 4));
        evC[u][2] = __builtin_nontemporal_load(reinterpret_cast<const f32x4*>(ap + 32));
        evC[u][3] = __builtin_nontemporal_load(reinterpret_cast<const f32x4*>(ap + 36));
        int erc = tt * 16 + el; if (erc > n_edges - 1) erc = n_edges - 1;
        srcC[u] = ei[erc];
        dstC[u] = ei[n_edges + erc];
    }

    for (int t = t0; t < t1; t += 2) {
        // ---- K/Q gathers for current pair (indices arrived an iter ago) ----
        u32x4 kb[2][2], qb[2][2];
#pragma unroll
        for (int u = 0; u < 2; ++u) {
            const unsigned* kp = Kbu + (size_t)srcC[u] * 32 + qg * 8;
            const unsigned* qp = Qbu + (size_t)dstC[u] * 32 + qg * 8;
            kb[u][0] = *reinterpret_cast<const u32x4*>(kp);
            kb[u][1] = *reinterpret_cast<const u32x4*>(kp + 4);
            qb[u][0] = *reinterpret_cast<const u32x4*>(qp);
            qb[u][1] = *reinterpret_cast<const u32x4*>(qp + 4);
        }

        // ---- prefetch pair t+2 (e rows + indices) ----
        {
            int tn = t + 2; if (tn > t1 - 1) tn = t1 - 1;
#pragma unroll
            for (int u = 0; u < 2; ++u) {
                int tt = tn + u; if (tt > ntiles - 1) tt = ntiles - 1;
                int arow = tt * 16 + r16; if (arow > n_edges - 1) arow = n_edges - 1;
                const float* ap = e + (size_t)arow * IN_EDGE + g4 * 8;
                evN[u][0] = __builtin_nontemporal_load(reinterpret_cast<const f32x4*>(ap));
                evN[u][1] = __builtin_nontemporal_load(reinterpret_cast<const f32x4*>(ap + 4));
                evN[u][2] = __builtin_nontemporal_load(reinterpret_cast<const f32x4*>(ap + 32));
                evN[u][3] = __builtin_nontemporal_load(reinterpret_cast<const f32x4*>(ap + 36));
                int erc = tt * 16 + el; if (erc > n_edges - 1) erc = n_edges - 1;
                srcN[u] = ei[erc];
                dstN[u] = ei[n_edges + erc];
            }
        }

        // ---- MFMA + LDS remap for both tiles of current pair ----
#pragma unroll
        for (int u = 0; u < 2; ++u) {
            bf16x8 afr[2];
            afr[0][0] = f2bf(evC[u][0].x); afr[0][1] = f2bf(evC[u][0].y);
            afr[0][2] = f2bf(evC[u][0].z); afr[0][3] = f2bf(evC[u][0].w);
            afr[0][4] = f2bf(evC[u][1].x); afr[0][5] = f2bf(evC[u][1].y);
            afr[0][6] = f2bf(evC[u][1].z); afr[0][7] = f2bf(evC[u][1].w);
            afr[1][0] = f2bf(evC[u][2].x); afr[1][1] = f2bf(evC[u][2].y);
            afr[1][2] = f2bf(evC[u][2].z); afr[1][3] = f2bf(evC[u][2].w);
            afr[1][4] = f2bf(evC[u][3].x); afr[1][5] = f2bf(evC[u][3].y);
            afr[1][6] = f2bf(evC[u][3].z); afr[1][7] = f2bf(evC[u][3].w);

            f32x4 acc[4] = {};
#pragma unroll
            for (int ct = 0; ct < 4; ++ct) {
                acc[ct] = __builtin_amdgcn_mfma_f32_16x16x32_bf16(afr[0], bfr[ct][0], acc[ct], 0, 0, 0);
                acc[ct] = __builtin_amdgcn_mfma_f32_16x16x32_bf16(afr[1], bfr[ct][1], acc[ct], 0, 0, 0);
            }
#pragma unroll
            for (int ct = 0; ct < 4; ++ct)
#pragma unroll
                for (int r = 0; r < 4; ++r)
                    plds[wid][u][g4 * 4 + r][ct * 16 + r16] = acc[ct][r] + bias[ct];
        }

        // one cross-lane LDS handoff per pair (same-wave DS ordering)
        asm volatile("s_waitcnt lgkmcnt(0)" ::: "memory");

        // ---- epilogues, both tiles ----
#pragma unroll
        for (int u = 0; u < 2; ++u) {
            const int tt = t + u;
            const int erow = tt * 16 + el;
            const bool valid = (tt < t1) && (erow < n_edges);

            const float* mrow = &plds[wid][u][el][qg * 16];
            f32x4 p0 = *reinterpret_cast<const f32x4*>(mrow);
            f32x4 p1 = *reinterpret_cast<const f32x4*>(mrow + 4);
            f32x4 p2 = *reinterpret_cast<const f32x4*>(mrow + 8);
            f32x4 p3 = *reinterpret_cast<const f32x4*>(mrow + 12);
            float pe[16];
            pe[0]=p0.x; pe[1]=p0.y; pe[2]=p0.z; pe[3]=p0.w;
            pe[4]=p1.x; pe[5]=p1.y; pe[6]=p1.z; pe[7]=p1.w;
            pe[8]=p2.x; pe[9]=p2.y; pe[10]=p2.z; pe[11]=p2.w;
            pe[12]=p3.x; pe[13]=p3.y; pe[14]=p3.z; pe[15]=p3.w;

            float sc[16];
#pragma unroll
            for (int half = 0; half < 2; ++half)
#pragma unroll
                for (int w = 0; w < 4; ++w) {
                    unsigned ku = kb[u][half][w];
                    unsigned qu = qb[u][half][w];
                    int c = half * 8 + 2 * w;
                    sc[c]     = fmaf(bflo(ku), bflo(qu), pe[c]);
                    sc[c + 1] = fmaf(bfhi(ku), bfhi(qu), pe[c + 1]);
                }

            if (valid) {
                float* op = e_out + (size_t)erow * HID + qg * 16;
                f32x4 s0 = {sc[0], sc[1], sc[2], sc[3]};
                f32x4 s1 = {sc[4], sc[5], sc[6], sc[7]};
                f32x4 s2 = {sc[8], sc[9], sc[10], sc[11]};
                f32x4 s3 = {sc[12], sc[13], sc[14], sc[15]};
                *reinterpret_cast<f32x4*>(op)      = s0;
                *reinterpret_cast<f32x4*>(op + 4)  = s1;
                *reinterpret_cast<f32x4*>(op + 8)  = s2;
                *reinterpret_cast<f32x4*>(op + 12) = s3;
            }

            float hs0 = ((sc[0] + sc[1]) + (sc[2] + sc[3])) + ((sc[4] + sc[5]) + (sc[6] + sc[7]));
            float hs1 = ((sc[8] + sc[9]) + (sc[10] + sc[11])) + ((sc[12] + sc[13]) + (sc[14] + sc[15]));
            float a0 = __expf(fminf(fmaxf(hs0, -5.0f), 5.0f));
            float a1 = __expf(fminf(fmaxf(hs1, -5.0f), 5.0f));
            if (valid) {
                atomicAdd(&z_sum[srcC[u] * HEADS + qg * 2], a0);
                atomicAdd(&z_sum[srcC[u] * HEADS + qg * 2 + 1], a1);
                if (qg == 0) atomicAdd(&cnt[srcC[u]], 1.0f);
            }
        }

        // ---- rotate pipeline ----
#pragma unroll
        for (int u = 0; u < 2; ++u) {
#pragma unroll
            for (int i = 0; i < 4; ++i) evC[u][i] = evN[u][i];
            srcC[u] = srcN[u]; dstC[u] = dstN[u];
        }
    }
}

// ---------------------------------------------------------------------------
// Finalize: h_out[n,h,d] = V[n,h,d]*S / (S/max(cnt,1) + 1e-6)
// ---------------------------------------------------------------------------
__global__ __launch_bounds__(256) void finalize_kernel(
    const float* __restrict__ V, const float* __restrict__ z_sum,
    const float* __restrict__ cnt, float* __restrict__ h_out, int total)
{
    int i = blockIdx.x * 256 + threadIdx.x;
    if (i >= total) return;
    int node = i >> 6;
    int head = (i >> 3) & 7;
    float S = z_sum[node * HEADS + head];
    float c = fmaxf(cnt[node], 1.0f);
    h_out[i] = V[i] * S / (S / c + 1e-6f);
}

extern "C" void kernel_launch(void* const* d_in, const int* in_sizes, int n_in,
                              void* d_out, int out_size, void* d_ws, size_t ws_size,
                              hipStream_t stream)
{
    const int*   ei = (const int*)d_in[0];
    const float* h  = (const float*)d_in[1];
    const float* e  = (const float*)d_in[2];
    const float* WQ = (const float*)d_in[3];
    const float* bQ = (const float*)d_in[4];
    const float* WK = (const float*)d_in[5];
    const float* bK = (const float*)d_in[6];
    const float* WV = (const float*)d_in[7];
    const float* bV = (const float*)d_in[8];
    const float* We = (const float*)d_in[9];
    const float* be = (const float*)d_in[10];

    const int n_nodes = in_sizes[1] / IN_NODE;   // 50000
    const int n_edges = in_sizes[2] / IN_EDGE;   // 800000

    float* out_h = (float*)d_out;                       // n_nodes*64
    float* out_e = out_h + (size_t)n_nodes * HID;       // n_edges*64

    unsigned short* Qb = (unsigned short*)d_ws;          // bf16, n*64
    unsigned short* Kb = Qb + (size_t)n_nodes * HID;     // bf16 (pre-scaled)
    float* V     = (float*)(Kb + (size_t)n_nodes * HID);
    float* z_sum = V + (size_t)n_nodes * HID;
    float* cnt   = z_sum + (size_t)n_nodes * HEADS;

    (void)hipMemsetAsync(z_sum, 0, (size_t)n_nodes * (HEADS + 1) * sizeof(float), stream);

    // QKV: 256 blocks x 4 waves x 3 mats
    {
        dim3 grid(256, 3);
        qkv_kernel<<<grid, 256, 0, stream>>>(h, WQ, bQ, WK, bK, WV, bV,
                                             Qb, Kb, V, n_nodes);
    }
    // Edge: 2048 blocks x 4 waves (R12 geometry — measured optimum)
    {
        const int nblk = 2048;
        const int nwaves = nblk * 4;
        const int ntiles = (n_edges + 15) >> 4;
        const int tpw = (ntiles + nwaves - 1) / nwaves;
        edge_kernel<<<nblk, 256, 0, stream>>>(ei, e, We, be, Qb, Kb,
                                              out_e, z_sum, cnt, n_edges, tpw);
    }
    // Finalize
    {
        const int total = n_nodes * HID;
        finalize_kernel<<<(total + 255) / 256, 256, 0, stream>>>(V, z_sum, cnt,
                                                                 out_h, total);
    }
}